// Round 2
// baseline (6771.369 us; speedup 1.0000x reference)
//
#include <hip/hip_runtime.h>
#include <hip/hip_bf16.h>

constexpr int B_ = 8, S_ = 1024, D_ = 1024, NH_ = 16, DH_ = 64;
constexpr float NEGV = -1e9f;

// ---------------------------------------------------------------------------
// Kernel 1: per-head Q/K/V projection.
// Q[b,n,s,e] = sum_d H[b,s,n*64+d] * Wq[n,e,d] + bq[n,e]   (layout B,NH,S,DH)
// grid: B*S*NH blocks of 64 threads (thread = e)
// ---------------------------------------------------------------------------
__global__ __launch_bounds__(64) void qkv_kernel(
    const float* __restrict__ H,
    const float* __restrict__ Wq, const float* __restrict__ bq,
    const float* __restrict__ Wk, const float* __restrict__ bk,
    const float* __restrict__ Wv, const float* __restrict__ bv,
    float* __restrict__ Q, float* __restrict__ K, float* __restrict__ V) {
  int idx = blockIdx.x;
  int n = idx % NH_;
  int bs = idx / NH_;
  int s = bs % S_;
  int b = bs / S_;
  int e = threadIdx.x;

  __shared__ float h[DH_];
  const float* Hrow = H + ((size_t)(b * S_ + s)) * D_ + n * DH_;
  h[e] = Hrow[e];
  __syncthreads();

  const float* wq = Wq + (size_t)(n * DH_ + e) * DH_;
  const float* wk = Wk + (size_t)(n * DH_ + e) * DH_;
  const float* wv = Wv + (size_t)(n * DH_ + e) * DH_;
  float aq = 0.f, ak = 0.f, av = 0.f;
#pragma unroll 8
  for (int d = 0; d < DH_; d++) {
    float hv = h[d];
    aq += hv * wq[d];
    ak += hv * wk[d];
    av += hv * wv[d];
  }
  size_t o = (((size_t)b * NH_ + n) * S_ + s) * DH_ + e;
  Q[o] = aq + bq[n * DH_ + e];
  K[o] = ak + bk[n * DH_ + e];
  V[o] = av + bv[n * DH_ + e];
}

// ---------------------------------------------------------------------------
// Kernel 2: scores row + mask + softmax -> A (fp32, layout NH,B,S,S)
// one block (256 thr) per (n,b,s) row; consecutive blocks share (n,b) K slice
// ---------------------------------------------------------------------------
__global__ __launch_bounds__(256) void attn_kernel(
    const float* __restrict__ Q, const float* __restrict__ K,
    const int* __restrict__ mask, float* __restrict__ A) {
  int idx = blockIdx.x;
  int s = idx % S_;
  int nb = idx / S_;
  int b = nb % B_;
  int n = nb / B_;
  int tid = threadIdx.x;

  __shared__ float q[DH_];
  __shared__ float sc[S_];
  __shared__ float red[256];

  const float* qrow = Q + (((size_t)b * NH_ + n) * S_ + s) * DH_;
  if (tid < DH_) q[tid] = qrow[tid];
  __syncthreads();

  const float* Kbase = K + (((size_t)b * NH_ + n) * S_) * DH_;
  const int* mrow = mask + ((size_t)b * S_ + s) * S_;

  for (int t = tid; t < S_; t += 256) {
    const float* krow = Kbase + (size_t)t * DH_;
    float acc = 0.f;
#pragma unroll 8
    for (int d = 0; d < DH_; d++) acc += q[d] * krow[d];
    acc *= 0.125f;  // 1/sqrt(64)
    if (mrow[t] == 0) acc = NEGV;
    sc[t] = acc;
  }
  __syncthreads();

  // block max
  float m = -INFINITY;
  for (int t = tid; t < S_; t += 256) m = fmaxf(m, sc[t]);
  red[tid] = m;
  __syncthreads();
  for (int w = 128; w > 0; w >>= 1) {
    if (tid < w) red[tid] = fmaxf(red[tid], red[tid + w]);
    __syncthreads();
  }
  m = red[0];
  __syncthreads();

  // exp + block sum
  float sum = 0.f;
  for (int t = tid; t < S_; t += 256) {
    float e = __expf(sc[t] - m);
    sc[t] = e;
    sum += e;
  }
  red[tid] = sum;
  __syncthreads();
  for (int w = 128; w > 0; w >>= 1) {
    if (tid < w) red[tid] += red[tid + w];
    __syncthreads();
  }
  float inv = 1.0f / red[0];

  float* arow = A + (((size_t)n * B_ + b) * S_ + s) * S_;
  for (int t = tid; t < S_; t += 256) arow[t] = sc[t] * inv;
}

// ---------------------------------------------------------------------------
// Kernel 3: heads[b,s,n,d] = sum_t A[n,b,s,t] * V[b,n,t,d]
// block: (b, n, 16-row s-tile). LDS-staged 16x64 A tile and 64x64 V tile.
// heads stored as concat layout (B,S,D) fp32.
// ---------------------------------------------------------------------------
__global__ __launch_bounds__(256) void pv_kernel(
    const float* __restrict__ A, const float* __restrict__ V,
    float* __restrict__ heads) {
  constexpr int ST = 16, TT = 64;
  int idx = blockIdx.x;
  int st = idx % (S_ / ST);
  int bn = idx / (S_ / ST);
  int n = bn % NH_;
  int b = bn / NH_;
  int tid = threadIdx.x;

  __shared__ float As[ST][TT];
  __shared__ float Vs[TT][DH_];

  int di = tid % DH_;   // output d
  int ii = tid / DH_;   // 0..3

  float acc[4] = {0.f, 0.f, 0.f, 0.f};
  const float* Abase = A + (((size_t)n * B_ + b) * S_ + st * ST) * S_;
  const float* Vbase = V + (((size_t)b * NH_ + n) * S_) * DH_;

  for (int t0 = 0; t0 < S_; t0 += TT) {
    for (int k = tid; k < ST * TT; k += 256) {
      int i = k / TT, j = k % TT;
      As[i][j] = Abase[(size_t)i * S_ + t0 + j];
    }
    for (int k = tid; k < TT * DH_; k += 256) {
      int j = k / DH_, d = k % DH_;
      Vs[j][d] = Vbase[(size_t)(t0 + j) * DH_ + d];
    }
    __syncthreads();
#pragma unroll 8
    for (int j = 0; j < TT; j++) {
      float v = Vs[j][di];  // consecutive banks across lanes
#pragma unroll
      for (int r = 0; r < 4; r++) acc[r] += As[ii + 4 * r][j] * v;  // broadcast
    }
    __syncthreads();
  }
  for (int r = 0; r < 4; r++) {
    int s = st * ST + ii + 4 * r;
    heads[((size_t)(b * S_ + s)) * D_ + n * DH_ + di] = acc[r];
  }
}

// ---------------------------------------------------------------------------
// Kernel 4: out[m,o] = sum_k heads[m,k] * Wo[o,k] + bo[o]   (M=B*S, 1024x1024)
// 32x32 output tile per block, K staged in 32-chunks.
// ---------------------------------------------------------------------------
__global__ __launch_bounds__(256) void oproj_kernel(
    const float* __restrict__ X, const float* __restrict__ Wo,
    const float* __restrict__ bo, float* __restrict__ out) {
  constexpr int TM = 32, TN = 32, TK = 32;
  int nt = blockIdx.x % (D_ / TN);
  int mt = blockIdx.x / (D_ / TN);
  int tid = threadIdx.x;

  __shared__ float Xs[TM][TK + 1];
  __shared__ float Ws[TN][TK + 1];

  int col = tid % TN;       // o within tile
  int row = tid / TN;       // 0..7
  float acc[4] = {0.f, 0.f, 0.f, 0.f};  // m = row + 8*r

  for (int k0 = 0; k0 < D_; k0 += TK) {
    for (int k = tid; k < TM * TK; k += 256) {
      int i = k / TK, kk = k % TK;
      Xs[i][kk] = X[(size_t)(mt * TM + i) * D_ + k0 + kk];
    }
    for (int k = tid; k < TN * TK; k += 256) {
      int i = k / TK, kk = k % TK;
      Ws[i][kk] = Wo[(size_t)(nt * TN + i) * D_ + k0 + kk];
    }
    __syncthreads();
#pragma unroll 8
    for (int kk = 0; kk < TK; kk++) {
      float w = Ws[col][kk];
#pragma unroll
      for (int r = 0; r < 4; r++) acc[r] += Xs[row + 8 * r][kk] * w;
    }
    __syncthreads();
  }
  float bias = bo[nt * TN + col];
  for (int r = 0; r < 4; r++) {
    int m = mt * TM + row + 8 * r;
    out[(size_t)m * D_ + nt * TN + col] = acc[r] + bias;
  }
}

// ---------------------------------------------------------------------------
extern "C" void kernel_launch(void* const* d_in, const int* in_sizes, int n_in,
                              void* d_out, int out_size, void* d_ws,
                              size_t ws_size, hipStream_t stream) {
  const float* H = (const float*)d_in[0];
  const int* mask = (const int*)d_in[1];
  const float* Wq = (const float*)d_in[2];
  const float* bq = (const float*)d_in[3];
  const float* Wk = (const float*)d_in[4];
  const float* bk = (const float*)d_in[5];
  const float* Wv = (const float*)d_in[6];
  const float* bv = (const float*)d_in[7];
  const float* Wo = (const float*)d_in[8];
  const float* bo = (const float*)d_in[9];

  float* out = (float*)d_out;                      // (B,S,D)
  float* A = out + (size_t)B_ * S_ * D_;           // (NH,B,S,S)

  const size_t qkv_elems = (size_t)B_ * NH_ * S_ * DH_;  // 8.4M
  float* Q = (float*)d_ws;
  float* K = Q + qkv_elems;
  float* V = K + qkv_elems;
  float* heads = V + qkv_elems;                    // (B,S,D) concat layout

  qkv_kernel<<<B_ * S_ * NH_, 64, 0, stream>>>(H, Wq, bq, Wk, bk, Wv, bv, Q, K, V);
  attn_kernel<<<NH_ * B_ * S_, 256, 0, stream>>>(Q, K, mask, A);
  pv_kernel<<<B_ * NH_ * (S_ / 16), 256, 0, stream>>>(A, V, heads);
  oproj_kernel<<<(B_ * S_ / 32) * (D_ / 32), 256, 0, stream>>>(heads, Wo, bo, out);
}

// Round 3
// 1486.669 us; speedup vs baseline: 4.5547x; 4.5547x over previous
//
#include <hip/hip_runtime.h>
#include <hip/hip_bf16.h>

typedef __bf16 v8bf __attribute__((ext_vector_type(8)));
typedef float v4f __attribute__((ext_vector_type(4)));

constexpr int B_ = 8, S_ = 1024, D_ = 1024, NH_ = 16, DH_ = 64;
constexpr float NEGV = -1e9f;

#define MFMA(a, b, c) __builtin_amdgcn_mfma_f32_16x16x32_bf16((a), (b), (c), 0, 0, 0)

__device__ __forceinline__ __bf16 tobf(float f) {
  unsigned u = __float_as_uint(f);
  u += 0x7fffu + ((u >> 16) & 1);
  unsigned short s = (unsigned short)(u >> 16);
  return __builtin_bit_cast(__bf16, s);
}

__device__ __forceinline__ v8bf cvt8(float4 a, float4 b) {
  v8bf r;
  r[0] = tobf(a.x); r[1] = tobf(a.y); r[2] = tobf(a.z); r[3] = tobf(a.w);
  r[4] = tobf(b.x); r[5] = tobf(b.y); r[6] = tobf(b.z); r[7] = tobf(b.w);
  return r;
}

// ---------------------------------------------------------------------------
// Kernel 0: pack mask (B,S,S) int32 -> bitmask u64 (bit t of row). 33.5MB -> 1MB
// so attn's two passes read 2x2MB instead of 2x537MB.
// ---------------------------------------------------------------------------
__global__ __launch_bounds__(256) void maskpack(const int* __restrict__ mask,
                                                unsigned long long* __restrict__ bits) {
  size_t base = (size_t)blockIdx.x * 256;
  int m = mask[base + threadIdx.x];
  unsigned long long w = __ballot(m != 0);
  if ((threadIdx.x & 63) == 0) bits[base / 64 + (threadIdx.x >> 6)] = w;
}

// ---------------------------------------------------------------------------
// Kernel 1: QKV projection via MFMA. Q,K stored (b,n,s,e) bf16; V stored
// TRANSPOSED (b,n,e,t) bf16 so PV's B-operand frags are k-contiguous.
// grid: rt + 16*(n + 16*b), 2048 blocks x 256 thr; wave owns 16 s-rows.
// ---------------------------------------------------------------------------
__global__ __launch_bounds__(256) void qkv_mfma(
    const float* __restrict__ H,
    const float* __restrict__ Wq, const float* __restrict__ bq,
    const float* __restrict__ Wk, const float* __restrict__ bk,
    const float* __restrict__ Wv, const float* __restrict__ bv,
    __bf16* __restrict__ Q, __bf16* __restrict__ K, __bf16* __restrict__ Vt) {
  int idx = blockIdx.x;
  int rt = idx & 15, n = (idx >> 4) & 15, b = idx >> 8;
  int tid = threadIdx.x, wave = tid >> 6, lane = tid & 63;
  int quad = lane >> 4, col = lane & 15;
  int s0 = rt * 64 + wave * 16;

  // A-frags: H rows (m = col), k = d contiguous. Loaded once, reused 12x.
  const float* Hrow = H + ((size_t)(b * S_ + s0 + col)) * D_ + n * DH_;
  v8bf af[2];
#pragma unroll
  for (int ks = 0; ks < 2; ks++) {
    const float* p = Hrow + ks * 32 + quad * 8;
    af[ks] = cvt8(*(const float4*)p, *(const float4*)(p + 4));
  }

  const float* Wm[3] = {Wq + n * 4096, Wk + n * 4096, Wv + n * 4096};
  const float* Bm[3] = {bq + n * 64, bk + n * 64, bv + n * 64};
  __bf16* Qdst = Q + ((size_t)(b * NH_ + n) * S_) * DH_;
  __bf16* Kdst = K + ((size_t)(b * NH_ + n) * S_) * DH_;
  __bf16* Vdst = Vt + ((size_t)(b * NH_ + n) * DH_) * S_;

  for (int w = 0; w < 3; w++) {
#pragma unroll
    for (int ct = 0; ct < 4; ct++) {
      int e = ct * 16 + col;
      v4f acc = {0.f, 0.f, 0.f, 0.f};
#pragma unroll
      for (int ks = 0; ks < 2; ks++) {
        // B[k=d][n=e] = W[e][d]: row e of W, k-contiguous
        const float* p = Wm[w] + (size_t)e * 64 + ks * 32 + quad * 8;
        acc = MFMA(af[ks], cvt8(*(const float4*)p, *(const float4*)(p + 4)), acc);
      }
      float bias = Bm[w][e];
      if (w == 0) {
#pragma unroll
        for (int g = 0; g < 4; g++)
          Qdst[(size_t)(s0 + quad * 4 + g) * DH_ + e] = tobf(acc[g] + bias);
      } else if (w == 1) {
#pragma unroll
        for (int g = 0; g < 4; g++)
          Kdst[(size_t)(s0 + quad * 4 + g) * DH_ + e] = tobf(acc[g] + bias);
      } else {
        // transposed store: Vt[e][s]
#pragma unroll
        for (int g = 0; g < 4; g++)
          Vdst[(size_t)e * S_ + s0 + quad * 4 + g] = tobf(acc[g] + bias);
      }
    }
  }
}

// ---------------------------------------------------------------------------
// Kernel 2: QK^T + mask + softmax -> A (fp32, layout NH,B,S,S).
// Two-pass online softmax, all state in registers, no LDS/barriers.
// Wave owns 16 Q-rows; loops 64 col-tiles of 16. grid n + 16*(st + 16*b).
// ---------------------------------------------------------------------------
__global__ __launch_bounds__(256) void attn_mfma(
    const __bf16* __restrict__ Q, const __bf16* __restrict__ K,
    const unsigned long long* __restrict__ mbits, float* __restrict__ A) {
  int idx = blockIdx.x;
  int n = idx & 15, st = (idx >> 4) & 15, b = idx >> 8;
  int tid = threadIdx.x, wave = tid >> 6, lane = tid & 63;
  int quad = lane >> 4, col = lane & 15;
  int s0 = st * 64 + wave * 16;

  const __bf16* Qb = Q + ((size_t)(b * NH_ + n) * S_ + s0 + col) * DH_;
  v8bf af0 = *(const v8bf*)(Qb + quad * 8);
  v8bf af1 = *(const v8bf*)(Qb + 32 + quad * 8);

  const __bf16* Kb = K + ((size_t)(b * NH_ + n) * S_) * DH_;
  const unsigned long long* mrow[4];
  float mx[4], l[4];
#pragma unroll
  for (int g = 0; g < 4; g++) {
    mx[g] = -INFINITY;
    l[g] = 0.f;
    mrow[g] = mbits + ((size_t)b * S_ + s0 + quad * 4 + g) * (S_ / 64);
  }

  // pass 1: online max + sum
  for (int ct = 0; ct < 64; ct++) {
    const __bf16* Kt = Kb + (size_t)(ct * 16 + col) * DH_;
    v4f acc = {0.f, 0.f, 0.f, 0.f};
    acc = MFMA(af0, *(const v8bf*)(Kt + quad * 8), acc);
    acc = MFMA(af1, *(const v8bf*)(Kt + 32 + quad * 8), acc);
    int word = ct >> 2, sh = (ct & 3) * 16 + col;
#pragma unroll
    for (int g = 0; g < 4; g++) {
      float v = ((mrow[g][word] >> sh) & 1ull) ? acc[g] * 0.125f : NEGV;
      float t = v;
      t = fmaxf(t, __shfl_xor(t, 1));
      t = fmaxf(t, __shfl_xor(t, 2));
      t = fmaxf(t, __shfl_xor(t, 4));
      t = fmaxf(t, __shfl_xor(t, 8));
      float mnew = fmaxf(mx[g], t);
      float e = __expf(v - mnew);
      e += __shfl_xor(e, 1);
      e += __shfl_xor(e, 2);
      e += __shfl_xor(e, 4);
      e += __shfl_xor(e, 8);
      l[g] = l[g] * __expf(mx[g] - mnew) + e;
      mx[g] = mnew;
    }
  }
  float inv[4];
#pragma unroll
  for (int g = 0; g < 4; g++) inv[g] = 1.f / l[g];

  // pass 2: recompute, normalize, write A
  float* Ab = A + (((size_t)n * B_ + b) * S_) * S_;
  for (int ct = 0; ct < 64; ct++) {
    const __bf16* Kt = Kb + (size_t)(ct * 16 + col) * DH_;
    v4f acc = {0.f, 0.f, 0.f, 0.f};
    acc = MFMA(af0, *(const v8bf*)(Kt + quad * 8), acc);
    acc = MFMA(af1, *(const v8bf*)(Kt + 32 + quad * 8), acc);
    int word = ct >> 2, sh = (ct & 3) * 16 + col;
#pragma unroll
    for (int g = 0; g < 4; g++) {
      float v = ((mrow[g][word] >> sh) & 1ull) ? acc[g] * 0.125f : NEGV;
      float a = __expf(v - mx[g]) * inv[g];
      Ab[(size_t)(s0 + quad * 4 + g) * S_ + ct * 16 + col] = a;
    }
  }
}

// ---------------------------------------------------------------------------
// Kernel 3: heads = A @ V via MFMA. A fp32 (from d_out), Vt bf16 transposed.
// Wave owns 16 s-rows x 64 d-cols; acc[4] persistent. No LDS.
// ---------------------------------------------------------------------------
__global__ __launch_bounds__(256) void pv_mfma(
    const float* __restrict__ A, const __bf16* __restrict__ Vt,
    __bf16* __restrict__ X) {
  int idx = blockIdx.x;
  int n = idx & 15, st = (idx >> 4) & 15, b = idx >> 8;
  int tid = threadIdx.x, wave = tid >> 6, lane = tid & 63;
  int quad = lane >> 4, col = lane & 15;
  int s0 = st * 64 + wave * 16;

  const float* Ab = A + (((size_t)n * B_ + b) * S_ + s0 + col) * S_;
  const __bf16* Vb = Vt + ((size_t)(b * NH_ + n) * DH_) * S_;

  v4f acc[4];
#pragma unroll
  for (int ct = 0; ct < 4; ct++) acc[ct] = {0.f, 0.f, 0.f, 0.f};

  for (int k0 = 0; k0 < S_; k0 += 32) {
    const float* p = Ab + k0 + quad * 8;
    v8bf a8 = cvt8(*(const float4*)p, *(const float4*)(p + 4));
#pragma unroll
    for (int ct = 0; ct < 4; ct++) {
      // B[k=t][n=d] = Vt[d][t]: row d, k-contiguous
      const __bf16* q = Vb + (size_t)(ct * 16 + col) * S_ + k0 + quad * 8;
      acc[ct] = MFMA(a8, *(const v8bf*)q, acc[ct]);
    }
  }
#pragma unroll
  for (int ct = 0; ct < 4; ct++)
#pragma unroll
    for (int g = 0; g < 4; g++)
      X[((size_t)(b * S_ + s0 + quad * 4 + g)) * D_ + n * 64 + ct * 16 + col] =
          tobf(acc[ct][g]);
}

// ---------------------------------------------------------------------------
// Kernel 4: out = X @ Wo^T + bo via MFMA. X bf16 (heads), Wo fp32.
// grid nt + 16*mt (nt inner for Wo L2 reuse), 2048 blocks.
// ---------------------------------------------------------------------------
__global__ __launch_bounds__(256) void oproj_mfma(
    const __bf16* __restrict__ X, const float* __restrict__ Wo,
    const float* __restrict__ bo, float* __restrict__ out) {
  int idx = blockIdx.x;
  int nt = idx & 15, mt = idx >> 4;
  int tid = threadIdx.x, wave = tid >> 6, lane = tid & 63;
  int quad = lane >> 4, col = lane & 15;
  int m0 = mt * 64 + wave * 16, o0 = nt * 64;

  const __bf16* Xb = X + (size_t)(m0 + col) * D_;

  v4f acc[4];
#pragma unroll
  for (int ct = 0; ct < 4; ct++) acc[ct] = {0.f, 0.f, 0.f, 0.f};

  for (int k0 = 0; k0 < D_; k0 += 32) {
    v8bf a8 = *(const v8bf*)(Xb + k0 + quad * 8);
#pragma unroll
    for (int ct = 0; ct < 4; ct++) {
      // B[k][n=o] = Wo[o][k]: row o of Wo, k-contiguous
      const float* p = Wo + (size_t)(o0 + ct * 16 + col) * D_ + k0 + quad * 8;
      acc[ct] = MFMA(a8, cvt8(*(const float4*)p, *(const float4*)(p + 4)), acc[ct]);
    }
  }
#pragma unroll
  for (int ct = 0; ct < 4; ct++) {
    int o = o0 + ct * 16 + col;
    float bias = bo[o];
#pragma unroll
    for (int g = 0; g < 4; g++)
      out[(size_t)(m0 + quad * 4 + g) * D_ + o] = acc[ct][g] + bias;
  }
}

// ---------------------------------------------------------------------------
extern "C" void kernel_launch(void* const* d_in, const int* in_sizes, int n_in,
                              void* d_out, int out_size, void* d_ws,
                              size_t ws_size, hipStream_t stream) {
  const float* H = (const float*)d_in[0];
  const int* mask = (const int*)d_in[1];
  const float* Wq = (const float*)d_in[2];
  const float* bq = (const float*)d_in[3];
  const float* Wk = (const float*)d_in[4];
  const float* bk = (const float*)d_in[5];
  const float* Wv = (const float*)d_in[6];
  const float* bv = (const float*)d_in[7];
  const float* Wo = (const float*)d_in[8];
  const float* bo = (const float*)d_in[9];

  float* out = (float*)d_out;                      // (B,S,D)
  float* A = out + (size_t)B_ * S_ * D_;           // (NH,B,S,S)

  const size_t qkv_elems = (size_t)B_ * NH_ * S_ * DH_;  // 8.4M
  unsigned long long* mbits = (unsigned long long*)d_ws;          // 1 MB
  __bf16* Q = (__bf16*)(mbits + (size_t)B_ * S_ * (S_ / 64));
  __bf16* K = Q + qkv_elems;
  __bf16* Vt = K + qkv_elems;
  __bf16* X = Vt + qkv_elems;                      // heads, (B,S,D) bf16

  maskpack<<<B_ * S_ * (S_ / 256), 256, 0, stream>>>(mask, mbits);
  qkv_mfma<<<B_ * NH_ * (S_ / 64), 256, 0, stream>>>(H, Wq, bq, Wk, bk, Wv, bv,
                                                     Q, K, Vt);
  attn_mfma<<<B_ * (S_ / 64) * NH_, 256, 0, stream>>>(Q, K, mbits, A);
  pv_mfma<<<B_ * (S_ / 64) * NH_, 256, 0, stream>>>(A, Vt, X);
  oproj_mfma<<<(B_ * S_ / 64) * (D_ / 64), 256, 0, stream>>>(X, Wo, bo, out);
}